// Round 11
// baseline (4110.691 us; speedup 1.0000x reference)
//
#include <hip/hip_runtime.h>
#include <cmath>

#define NB 128  // batch

#define H_STRIDE 600     // floats per (b,ci) h plane: 24 rows x 25 pad
#define W_SLAB   5184    // floats per (g,ci) wt slab: 81 taps x 64 ch (split-half layout)

// ---------------------------------------------------------------------------
// conv1: x[128,3,32,32] -> h[128,256,(24x25 pad)] = relu(conv(x,w)+bias)
// ---------------------------------------------------------------------------
__global__ __launch_bounds__(192) void conv1_kernel(
    const float* __restrict__ x, const float* __restrict__ w,
    const float* __restrict__ bias, float* __restrict__ h)
{
    __shared__ float4 xs4[768];              // 3*32*32 floats
    float* xs = (float*)xs4;
    int b = blockIdx.x, cobase = blockIdx.y * 8, tid = threadIdx.x;
    const float4* xsrc = (const float4*)(x + (size_t)b * 3072);
    for (int i = tid; i < 768; i += 192) xs4[i] = xsrc[i];
    __syncthreads();
    for (int round = 0; round < 3; ++round) {
        int px = round * 192 + tid;          // 0..575
        int yy = px / 24, xx = px - yy * 24;
        float acc[8];
        #pragma unroll
        for (int cc = 0; cc < 8; ++cc) acc[cc] = 0.f;
        for (int c = 0; c < 3; ++c)
            for (int ky = 0; ky < 9; ++ky) {
                const float* xr = xs + c * 1024 + (yy + ky) * 32 + xx;
                float xv[9];
                #pragma unroll
                for (int kx = 0; kx < 9; ++kx) xv[kx] = xr[kx];
                int tb = c * 81 + ky * 9;
                #pragma unroll
                for (int cc = 0; cc < 8; ++cc) {
                    const float* wp = w + (cobase + cc) * 243 + tb;  // wave-uniform -> s_load
                    #pragma unroll
                    for (int kx = 0; kx < 9; ++kx) acc[cc] += xv[kx] * wp[kx];
                }
            }
        #pragma unroll
        for (int cc = 0; cc < 8; ++cc)
            h[((size_t)b * 256 + cobase + cc) * H_STRIDE + yy * 25 + xx] =
                fmaxf(acc[cc] + bias[cobase + cc], 0.f);
    }
}

// ---------------------------------------------------------------------------
// prim weight transpose: prim_w[512,256,81] -> wt[g][ci][tap][64] split-half:
//   ch = q*4 + r (q=0..15): r<2 -> tap*64 + 2q + r ; r>=2 -> tap*64 + 32 + 2q + (r-2)
// Both sides coalesced via LDS tile buf[64][82].
// ---------------------------------------------------------------------------
__global__ __launch_bounds__(128) void primw_transpose_kernel(
    const float* __restrict__ pw, float* __restrict__ wt)
{
    __shared__ float buf[64 * 82];           // 21 KB
    int g = blockIdx.x >> 8, ci = blockIdx.x & 255, tid = threadIdx.x;
    for (int idx = tid; idx < 5184; idx += 128) {
        int ch = idx / 81, t = idx - ch * 81;
        buf[ch * 82 + t] = pw[((size_t)(g * 64 + ch) * 256 + ci) * 81 + t];
    }
    __syncthreads();
    float* dst = wt + (size_t)(g * 256 + ci) * W_SLAB;
    for (int f = tid; f < W_SLAB; f += 128) {
        int tap = f >> 6;
        int rem = f & 63;
        int half = rem >> 5;                 // 0 = lo pair, 1 = hi pair
        int e = rem & 31;
        int q = e >> 1, j = e & 1;
        int ch = q * 4 + half * 2 + j;
        dst[f] = buf[ch * 82 + tap];
    }
}

// ---------------------------------------------------------------------------
// primary capsules: 2 images per block, DOUBLE-BUFFERED LDS (one barrier/ci).
// grid (64 b2, 8 g, 2 half), 256 thr; waves 0-1 -> img 0, 2-3 -> img 1;
// each thread 4ch x 8px. STAGE(ci+1 -> alt buffer) issues BEFORE compute(ci)
// so global->LDS latency hides under ~2600 VALU cycles of FMA.
// part[((half*128+b)*8+g)*4096 + c64*64+px]
// ---------------------------------------------------------------------------
__global__ __launch_bounds__(256) void prim_conv_kernel(
    const float* __restrict__ h, const float* __restrict__ wt,
    float* __restrict__ part)
{
    __shared__ __align__(16) float wsh[2 * W_SLAB];    // 2 x 5184 floats
    __shared__ __align__(16) float hsh[4 * H_STRIDE];  // 2 bufs x 2 imgs x 600
    int b2 = blockIdx.x, g = blockIdx.y, half = blockIdx.z, tid = threadIdx.x;
    int ci0 = half * 128;
    int img = tid >> 7;              // 0..1 (wave-uniform)
    int t128 = tid & 127;
    int quad = t128 & 15;            // 4-channel group: ch = quad*4 .. quad*4+3
    int prow = t128 >> 4;            // output row 0..7 (8 px)
    int b = b2 * 2 + img;
    int wlo = 2 * quad;              // lo-pair offset within tap record
    int whi = 32 + 2 * quad;         // hi-pair offset

    float acc[4][8];
    #pragma unroll
    for (int i = 0; i < 4; ++i)
        #pragma unroll
        for (int j = 0; j < 8; ++j) acc[i][j] = 0.f;

    // STAGE ci into buffer B (0/1): w -> wsh[B*5184..], h pair -> hsh[B*1200..]
    #define STAGE(ci, B)                                                                     \
    {                                                                                        \
        const float* wsrc = wt + (size_t)(g * 256 + (ci)) * W_SLAB;                          \
        const float* h0src = h + ((size_t)(b2 * 2 + 0) * 256 + (ci)) * H_STRIDE;             \
        const float* h1src = h + ((size_t)(b2 * 2 + 1) * 256 + (ci)) * H_STRIDE;             \
        unsigned int* wdst = (unsigned int*)(wsh + (B) * W_SLAB);                            \
        unsigned int* hdst = (unsigned int*)(hsh + (B) * 2 * H_STRIDE);                      \
        _Pragma("unroll")                                                                    \
        for (int k = 0; k < 6; ++k) {                                                        \
            int ix = k * 256 + tid;                                                          \
            if (ix < 1296)                                                                   \
                __builtin_amdgcn_global_load_lds(                                            \
                    (const unsigned int*)wsrc + ix * 4, wdst + ix * 4, 16, 0, 0);            \
        }                                                                                    \
        if (tid < 150)                                                                       \
            __builtin_amdgcn_global_load_lds(                                                \
                (const unsigned int*)h0src + tid * 4, hdst + tid * 4, 16, 0, 0);             \
        if (tid < 150)                                                                       \
            __builtin_amdgcn_global_load_lds(                                                \
                (const unsigned int*)h1src + tid * 4,                                        \
                hdst + (H_STRIDE + tid * 4 - tid * 4) + 600 + tid * 4, 16, 0, 0);            \
    }

    // prologue: fill buffer 0
    {
        const float* wsrc = wt + (size_t)(g * 256 + ci0) * W_SLAB;
        const float* h0src = h + ((size_t)(b2 * 2 + 0) * 256 + ci0) * H_STRIDE;
        const float* h1src = h + ((size_t)(b2 * 2 + 1) * 256 + ci0) * H_STRIDE;
        #pragma unroll
        for (int k = 0; k < 6; ++k) {
            int ix = k * 256 + tid;
            if (ix < 1296)
                __builtin_amdgcn_global_load_lds(
                    (const unsigned int*)wsrc + ix * 4, (unsigned int*)wsh + ix * 4, 16, 0, 0);
        }
        if (tid < 150)
            __builtin_amdgcn_global_load_lds(
                (const unsigned int*)h0src + tid * 4, (unsigned int*)hsh + tid * 4, 16, 0, 0);
        if (tid < 150)
            __builtin_amdgcn_global_load_lds(
                (const unsigned int*)h1src + tid * 4,
                (unsigned int*)(hsh + H_STRIDE) + tid * 4, 16, 0, 0);
    }
    asm volatile("s_waitcnt vmcnt(0)" ::: "memory");
    __syncthreads();

    for (int ci = ci0; ci < ci0 + 128; ++ci) {
        int cur = (ci - ci0) & 1;
        // issue next-tile stage into the other buffer (latency hidden by compute)
        if (ci + 1 < ci0 + 128) {
            int nb = cur ^ 1;
            const float* wsrc = wt + (size_t)(g * 256 + ci + 1) * W_SLAB;
            const float* h0src = h + ((size_t)(b2 * 2 + 0) * 256 + ci + 1) * H_STRIDE;
            const float* h1src = h + ((size_t)(b2 * 2 + 1) * 256 + ci + 1) * H_STRIDE;
            unsigned int* wdst = (unsigned int*)(wsh + nb * W_SLAB);
            unsigned int* hdst = (unsigned int*)(hsh + nb * 2 * H_STRIDE);
            #pragma unroll
            for (int k = 0; k < 6; ++k) {
                int ix = k * 256 + tid;
                if (ix < 1296)
                    __builtin_amdgcn_global_load_lds(
                        (const unsigned int*)wsrc + ix * 4, wdst + ix * 4, 16, 0, 0);
            }
            if (tid < 150)
                __builtin_amdgcn_global_load_lds(
                    (const unsigned int*)h0src + tid * 4, hdst + tid * 4, 16, 0, 0);
            if (tid < 150)
                __builtin_amdgcn_global_load_lds(
                    (const unsigned int*)h1src + tid * 4, hdst + 600 + tid * 4, 16, 0, 0);
        }
        // compute from current buffer
        const float* wbuf = wsh + cur * W_SLAB;
        const float* hbuf = hsh + cur * 2 * H_STRIDE + img * H_STRIDE;
        #pragma unroll 3
        for (int ky = 0; ky < 9; ++ky) {
            const float* hp = hbuf + (2 * prow + ky) * 25;
            float hv[23];
            #pragma unroll
            for (int t = 0; t < 23; ++t) hv[t] = hp[t];
            #pragma unroll
            for (int kx = 0; kx < 9; ++kx) {
                const float* wp = wbuf + (ky * 9 + kx) * 64;
                float2 wa = *(const float2*)(wp + wlo);
                float2 wb = *(const float2*)(wp + whi);
                float wv[4] = {wa.x, wa.y, wb.x, wb.y};
                #pragma unroll
                for (int j = 0; j < 8; ++j) {
                    float hx = hv[2 * j + kx];
                    #pragma unroll
                    for (int i = 0; i < 4; ++i) acc[i][j] += wv[i] * hx;
                }
            }
        }
        asm volatile("s_waitcnt vmcnt(0)" ::: "memory");  // next-buffer stage complete
        __syncthreads();  // all waves done with cur; staged data visible
    }
    #undef STAGE

    float* pp = part + ((size_t)(half * 128 + b) * 8 + g) * 4096;
    #pragma unroll
    for (int i = 0; i < 4; ++i) {
        int c64 = quad * 4 + i;
        *(float4*)(pp + c64 * 64 + prow * 8) =
            make_float4(acc[i][0], acc[i][1], acc[i][2], acc[i][3]);
        *(float4*)(pp + c64 * 64 + prow * 8 + 4) =
            make_float4(acc[i][4], acc[i][5], acc[i][6], acc[i][7]);
    }
}

// ---------------------------------------------------------------------------
// combine halves + bias + squash over capsule dim -> ut[b][r][8]
// ---------------------------------------------------------------------------
__global__ void squash_u_kernel(const float* __restrict__ part,
                                const float* __restrict__ pb, float* __restrict__ ut)
{
    int b = blockIdx.x; int r = blockIdx.y * 256 + threadIdx.x;
    int c64 = r >> 6;
    const float* p0 = part + (size_t)b * 8 * 4096 + r;
    const float* p1 = part + (size_t)(128 + b) * 8 * 4096 + r;
    float v[8]; float sq = 0.f;
    #pragma unroll
    for (int i = 0; i < 8; ++i) {
        v[i] = p0[(size_t)i * 4096] + p1[(size_t)i * 4096] + pb[i * 64 + c64];
        sq += v[i] * v[i];
    }
    float sc = sqrtf(sq) / (1.f + sq);
    float4 o0 = make_float4(v[0] * sc, v[1] * sc, v[2] * sc, v[3] * sc);
    float4 o1 = make_float4(v[4] * sc, v[5] * sc, v[6] * sc, v[7] * sc);
    float* o = ut + ((size_t)b * 4096 + r) * 8;
    *(float4*)o = o0; *(float4*)(o + 4) = o1;
}

// ---------------------------------------------------------------------------
// softmax stats over r (4096) per (c,b) row of logits
// ---------------------------------------------------------------------------
__global__ void softmax_stats_kernel(const float* __restrict__ logits,
                                     float* __restrict__ mbuf, float* __restrict__ sebuf)
{
    int cb = blockIdx.x; int tid = threadIdx.x;
    const float* lrow = logits + (size_t)cb * 4096;
    float mx = -1e30f;
    for (int i = tid; i < 4096; i += 256) mx = fmaxf(mx, lrow[i]);
    #pragma unroll
    for (int d = 1; d < 64; d <<= 1) mx = fmaxf(mx, __shfl_xor(mx, d));
    __shared__ float rm[4], rs[4];
    if ((tid & 63) == 0) rm[tid >> 6] = mx;
    __syncthreads();
    mx = fmaxf(fmaxf(rm[0], rm[1]), fmaxf(rm[2], rm[3]));
    float s = 0.f;
    for (int i = tid; i < 4096; i += 256) s += expf(lrow[i] - mx);
    #pragma unroll
    for (int d = 1; d < 64; d <<= 1) s += __shfl_xor(s, d);
    if ((tid & 63) == 0) rs[tid >> 6] = s;
    __syncthreads();
    if (tid == 0) {
        mbuf[cb] = mx;
        sebuf[cb] = rs[0] + rs[1] + rs[2] + rs[3];
    }
}

// ---------------------------------------------------------------------------
// routing phase A (R5-proven): per (c, 32-r chunk) partial s, deterministic
// ---------------------------------------------------------------------------
__global__ __launch_bounds__(256) void route_s_kernel(
    const float* __restrict__ logits, const float* __restrict__ ut,
    const float* __restrict__ route_w, const float* __restrict__ mbuf,
    const float* __restrict__ sebuf, float* __restrict__ spart)
{
    __shared__ __align__(16) float smem[11232];
    const int UB = 4224, PB = 8400, RB = 8928;
    int c = blockIdx.x, ch = blockIdx.y, tid = threadIdx.x;
    int r0 = ch * 32;

    {
        const float4* w4 = (const float4*)(route_w + ((size_t)c * 4096 + r0) * 128);
        #pragma unroll
        for (int k = 0; k < 4; ++k) {
            int idx = k * 256 + tid;
            float4 wv = w4[idx];
            int rl = idx >> 5, rem = (idx & 31) * 4;
            *(float4*)(smem + rl * 132 + rem) = wv;
        }
    }

    int bC = tid & 15, igC = (tid >> 4) & 7, ohC = tid >> 7;

    for (int bg = 0; bg < 8; ++bg) {
        int b0 = bg * 16;
        __syncthreads();
        {
            int bb = tid >> 4, seg = tid & 15;
            const float4* us = (const float4*)(ut + (size_t)(b0 + bb) * 32768 + (size_t)r0 * 8);
            #pragma unroll
            for (int q = 0; q < 4; ++q) {
                float4 v = us[seg * 4 + q];
                int base = UB + bb * 261 + (seg * 4 + q) * 4;
                smem[base + 0] = v.x; smem[base + 1] = v.y;
                smem[base + 2] = v.z; smem[base + 3] = v.w;
            }
        }
        if (tid < 128) {
            int b = tid >> 3, rr = tid & 7;
            int cb = c * 128 + b0 + b;
            float m = mbuf[cb];
            float inv = 1.0f / sebuf[cb];
            float4 lv = *(const float4*)(logits + (size_t)cb * 4096 + r0 + rr * 4);
            int pbb = PB + b * 33 + rr * 4;
            smem[pbb + 0] = expf(lv.x - m) * inv;
            smem[pbb + 1] = expf(lv.y - m) * inv;
            smem[pbb + 2] = expf(lv.z - m) * inv;
            smem[pbb + 3] = expf(lv.w - m) * inv;
        }
        __syncthreads();
        float4 a0 = make_float4(0.f, 0.f, 0.f, 0.f);
        float4 a1 = make_float4(0.f, 0.f, 0.f, 0.f);
        int ub = UB + bC * 261 + igC;
        int wb = igC * 16 + ohC * 8;
        int pbb = PB + bC * 33;
        for (int rl = 0; rl < 32; ++rl) {
            float uu = smem[ub + rl * 8];
            float pr = smem[pbb + rl];
            float t1 = pr * uu;
            const float* wp = smem + rl * 132 + wb;
            float4 w0 = *(const float4*)wp;
            float4 w1 = *(const float4*)(wp + 4);
            a0.x += t1 * w0.x; a0.y += t1 * w0.y; a0.z += t1 * w0.z; a0.w += t1 * w0.w;
            a1.x += t1 * w1.x; a1.y += t1 * w1.y; a1.z += t1 * w1.z; a1.w += t1 * w1.w;
        }
        int rb = RB + tid * 9;
        smem[rb + 0] = a0.x; smem[rb + 1] = a0.y; smem[rb + 2] = a0.z; smem[rb + 3] = a0.w;
        smem[rb + 4] = a1.x; smem[rb + 5] = a1.y; smem[rb + 6] = a1.z; smem[rb + 7] = a1.w;
        __syncthreads();
        {
            int o = tid & 15, b = tid >> 4;
            int oh = o >> 3, ol = o & 7;
            float s = 0.f;
            #pragma unroll
            for (int ig = 0; ig < 8; ++ig)
                s += smem[RB + (b + 16 * ig + 128 * oh) * 9 + ol];
            spart[(size_t)ch * 20480 + (size_t)(c * 128 + b0 + b) * 16 + o] = s;
        }
    }
}

// ---------------------------------------------------------------------------
// routing phase B: s = sum_ch spart (fixed order), v = squash(s) per (c,b)
// ---------------------------------------------------------------------------
__global__ void route_v_kernel(const float* __restrict__ spart, float* __restrict__ vbuf)
{
    int cb = blockIdx.x * 64 + threadIdx.x;  // 1280
    float4 a0 = make_float4(0,0,0,0), a1 = make_float4(0,0,0,0);
    float4 a2 = make_float4(0,0,0,0), a3 = make_float4(0,0,0,0);
    for (int k = 0; k < 128; ++k) {
        const float4* p = (const float4*)(spart + (size_t)k * 20480 + (size_t)cb * 16);
        float4 b0 = p[0], b1 = p[1], b2 = p[2], b3 = p[3];
        a0.x += b0.x; a0.y += b0.y; a0.z += b0.z; a0.w += b0.w;
        a1.x += b1.x; a1.y += b1.y; a1.z += b1.z; a1.w += b1.w;
        a2.x += b2.x; a2.y += b2.y; a2.z += b2.z; a2.w += b2.w;
        a3.x += b3.x; a3.y += b3.y; a3.z += b3.z; a3.w += b3.w;
    }
    float sq = a0.x*a0.x + a0.y*a0.y + a0.z*a0.z + a0.w*a0.w
             + a1.x*a1.x + a1.y*a1.y + a1.z*a1.z + a1.w*a1.w
             + a2.x*a2.x + a2.y*a2.y + a2.z*a2.z + a2.w*a2.w
             + a3.x*a3.x + a3.y*a3.y + a3.z*a3.z + a3.w*a3.w;
    float sc = sqrtf(sq) / (1.f + sq);
    float4* vp = (float4*)(vbuf + (size_t)cb * 16);
    vp[0] = make_float4(a0.x*sc, a0.y*sc, a0.z*sc, a0.w*sc);
    vp[1] = make_float4(a1.x*sc, a1.y*sc, a1.z*sc, a1.w*sc);
    vp[2] = make_float4(a2.x*sc, a2.y*sc, a2.z*sc, a2.w*sc);
    vp[3] = make_float4(a3.x*sc, a3.y*sc, a3.z*sc, a3.w*sc);
}

// ---------------------------------------------------------------------------
// routing phase C (R5-proven): logits += prior . v
// ---------------------------------------------------------------------------
__global__ __launch_bounds__(256) void route_upd_kernel(
    float* __restrict__ logits, const float* __restrict__ ut,
    const float* __restrict__ route_w, const float* __restrict__ vbuf)
{
    __shared__ __align__(16) float smem[8400];   // wch 4224 + ubuf 4176
    const int UB = 4224;
    int c = blockIdx.x, ch = blockIdx.y, tid = threadIdx.x;
    int r0 = ch * 32;
    {
        const float4* w4 = (const float4*)(route_w + ((size_t)c * 4096 + r0) * 128);
        #pragma unroll
        for (int k = 0; k < 4; ++k) {
            int idx = k * 256 + tid;
            float4 wv = w4[idx];
            int rl = idx >> 5, rem = (idx & 31) * 4;
            *(float4*)(smem + rl * 132 + rem) = wv;
        }
    }
    int b = tid & 15, rg = tid >> 4;
    for (int bg = 0; bg < 8; ++bg) {
        int b0 = bg * 16;
        __syncthreads();
        {
            int bb = tid >> 4, seg = tid & 15;
            const float4* us = (const float4*)(ut + (size_t)(b0 + bb) * 32768 + (size_t)r0 * 8);
            #pragma unroll
            for (int q = 0; q < 4; ++q) {
                float4 v = us[seg * 4 + q];
                int base = UB + bb * 261 + (seg * 4 + q) * 4;
                smem[base + 0] = v.x; smem[base + 1] = v.y;
                smem[base + 2] = v.z; smem[base + 3] = v.w;
            }
        }
        __syncthreads();
        int cb = c * 128 + b0 + b;
        const float4* vp = (const float4*)(vbuf + (size_t)cb * 16);
        float4 v0 = vp[0], v1 = vp[1], v2 = vp[2], v3 = vp[3];
        #pragma unroll
        for (int jj = 0; jj < 2; ++jj) {
            int rl = rg * 2 + jj;
            float4 p0 = make_float4(0,0,0,0), p1 = make_float4(0,0,0,0);
            float4 p2 = make_float4(0,0,0,0), p3 = make_float4(0,0,0,0);
            int ub = UB + b * 261 + rl * 8;
            #pragma unroll
            for (int i = 0; i < 8; ++i) {
                float uu = smem[ub + i];
                const float* wp = smem + rl * 132 + i * 16;
                float4 w0 = *(const float4*)wp;
                float4 w1 = *(const float4*)(wp + 4);
                float4 w2 = *(const float4*)(wp + 8);
                float4 w3 = *(const float4*)(wp + 12);
                p0.x += uu*w0.x; p0.y += uu*w0.y; p0.z += uu*w0.z; p0.w += uu*w0.w;
                p1.x += uu*w1.x; p1.y += uu*w1.y; p1.z += uu*w1.z; p1.w += uu*w1.w;
                p2.x += uu*w2.x; p2.y += uu*w2.y; p2.z += uu*w2.z; p2.w += uu*w2.w;
                p3.x += uu*w3.x; p3.y += uu*w3.y; p3.z += uu*w3.z; p3.w += uu*w3.w;
            }
            float delta = p0.x*v0.x + p0.y*v0.y + p0.z*v0.z + p0.w*v0.w
                        + p1.x*v1.x + p1.y*v1.y + p1.z*v1.z + p1.w*v1.w
                        + p2.x*v2.x + p2.y*v2.y + p2.z*v2.z + p2.w*v2.w
                        + p3.x*v3.x + p3.y*v3.y + p3.z*v3.z + p3.w*v3.w;
            logits[(size_t)cb * 4096 + r0 + rl] += delta;
        }
    }
}

// ---------------------------------------------------------------------------
// classes softmax + argmax one-hot mask -> z
// ---------------------------------------------------------------------------
__global__ void caps_out_kernel(const float* __restrict__ vbuf,
                                float* __restrict__ out_classes, float* __restrict__ zbuf)
{
    int b = threadIdx.x;  // 128
    float norms[10];
    #pragma unroll
    for (int c = 0; c < 10; ++c) {
        const float* vp = vbuf + (size_t)(c * 128 + b) * 16;
        float sq = 0.f;
        #pragma unroll
        for (int o = 0; o < 16; ++o) sq += vp[o] * vp[o];
        norms[c] = sqrtf(sq);
    }
    float mx = norms[0]; int am = 0;
    #pragma unroll
    for (int c = 1; c < 10; ++c) if (norms[c] > mx) { mx = norms[c]; am = c; }
    float se = 0.f; float e[10];
    #pragma unroll
    for (int c = 0; c < 10; ++c) { e[c] = expf(norms[c] - mx); se += e[c]; }
    float isd = 1.f / se;
    #pragma unroll
    for (int c = 0; c < 10; ++c) out_classes[b * 10 + c] = e[c] * isd;
    #pragma unroll
    for (int c = 0; c < 10; ++c) {
        const float* vp = vbuf + (size_t)(c * 128 + b) * 16;
        #pragma unroll
        for (int o = 0; o < 16; ++o)
            zbuf[b * 160 + c * 16 + o] = (c == am) ? vp[o] : 0.f;
    }
}

// ---------------------------------------------------------------------------
// generator stage 1: z[128,160] x g1_w[160,256*16] -> t1[128,4096]
// ---------------------------------------------------------------------------
__global__ void gen1_kernel(const float* __restrict__ z, const float* __restrict__ w,
                            float* __restrict__ out)
{
    int idx = blockIdx.x * 256 + threadIdx.x;  // 524288
    int j = idx & 4095; int b = idx >> 12;
    const float* zp = z + b * 160;
    float a = 0.f;
    #pragma unroll 4
    for (int ci = 0; ci < 160; ++ci) a += zp[ci] * w[(size_t)ci * 4096 + j];
    out[idx] = a;
}

// ---------------------------------------------------------------------------
// batchnorm stats (training-mode) per channel over (N,H,W)
// ---------------------------------------------------------------------------
template <int C, int HW>
__global__ void bn_stats_kernel(const float* __restrict__ t, const float* __restrict__ g,
                                const float* __restrict__ beta,
                                float* __restrict__ scale, float* __restrict__ shift)
{
    int co = blockIdx.x; int tid = threadIdx.x;
    float s = 0.f, s2 = 0.f;
    for (int i = tid; i < NB * HW; i += 256) {
        int b = i / HW, hw = i - b * HW;
        float v = t[((size_t)b * C + co) * HW + hw];
        s += v; s2 += v * v;
    }
    #pragma unroll
    for (int d = 1; d < 64; d <<= 1) { s += __shfl_xor(s, d); s2 += __shfl_xor(s2, d); }
    __shared__ float rs[4], rs2[4];
    if ((tid & 63) == 0) { rs[tid >> 6] = s; rs2[tid >> 6] = s2; }
    __syncthreads();
    if (tid == 0) {
        float S = rs[0] + rs[1] + rs[2] + rs[3];
        float S2 = rs2[0] + rs2[1] + rs2[2] + rs2[3];
        const float n = (float)(NB * HW);
        float mean = S / n;
        float var = S2 / n - mean * mean;
        float r = 1.f / sqrtf(var + 1e-5f);
        scale[co] = g[co] * r;
        shift[co] = beta[co] - mean * g[co] * r;
    }
}

template <int C, int HW>
__global__ void bn_apply_kernel(float* __restrict__ t, const float* __restrict__ scale,
                                const float* __restrict__ shift, int total)
{
    int idx = blockIdx.x * 256 + threadIdx.x;
    if (idx < total) {
        int co = (idx / HW) % C;
        t[idx] = fmaxf(t[idx] * scale[co] + shift[co], 0.f);
    }
}

// ---------------------------------------------------------------------------
// LDS-staged transposed conv (k=4,s=2,p=1): thread owns one (co,oy) row.
// ---------------------------------------------------------------------------
template <int Ci, int Co, int S, int SPLIT>
__global__ __launch_bounds__(256) void deconv_row_kernel(
    const float* __restrict__ in, const float* __restrict__ w,
    float* __restrict__ out)
{
    constexpr int OS = 2 * S;
    constexpr int ROWS = Co * OS;
    constexpr int RPB = ROWS / SPLIT;
    __shared__ __align__(16) float ish[Ci * S * S];
    int b = blockIdx.x, rb = blockIdx.y, tid = threadIdx.x;
    const float4* src = (const float4*)(in + (size_t)b * Ci * S * S);
    for (int i = tid; i < Ci * S * S / 4; i += 256) ((float4*)ish)[i] = src[i];
    __syncthreads();

    for (int r = rb * RPB + tid; r < (rb + 1) * RPB; r += 256) {
        int co = r / OS, oy = r % OS;
        float acc[OS];
        #pragma unroll
        for (int j = 0; j < OS; ++j) acc[j] = 0.f;
        int p = (oy + 1) & 1;                      // ky parity
        for (int ci = 0; ci < Ci; ++ci) {
            const float* wci = w + ((size_t)ci * Co + co) * 16;
            #pragma unroll
            for (int t = 0; t < 2; ++t) {
                int ky = p + 2 * t;
                int iy = (oy + 1 - ky) >> 1;       // exact (even numerator)
                if (iy < 0 || iy >= S) continue;
                float4 wv = *(const float4*)(wci + ky * 4);
                const float* irow = ish + (ci * S + iy) * S;
                #pragma unroll
                for (int ox = 0; ox < OS; ++ox) {
                    int q = (ox + 1) & 1;
                    int ix0 = (ox + 1 - q) >> 1;   // kx = q
                    int ix1 = ix0 - 1;             // kx = q+2
                    float wk0 = q ? wv.y : wv.x;
                    float wk2 = q ? wv.w : wv.z;
                    if (ix0 < S)  acc[ox] += wk0 * irow[ix0];
                    if (ix1 >= 0) acc[ox] += wk2 * irow[ix1];
                }
            }
        }
        float* orow = out + ((size_t)(b * Co + co) * OS + oy) * OS;
        #pragma unroll
        for (int j = 0; j < OS; j += 4)
            *(float4*)(orow + j) = make_float4(acc[j], acc[j+1], acc[j+2], acc[j+3]);
    }
}

// ---------------------------------------------------------------------------
// naive transposed conv (final stage 4 with tanh)
// ---------------------------------------------------------------------------
template <int Ci, int Co, int S, bool TANH>
__global__ void deconv_kernel(const float* __restrict__ in, const float* __restrict__ w,
                              float* __restrict__ out)
{
    constexpr int OS = 2 * S;
    int idx = blockIdx.x * 256 + threadIdx.x;  // NB*Co*OS*OS
    int ox = idx % OS; int t = idx / OS;
    int oy = t % OS; int t2 = t / OS;
    int co = t2 % Co; int b = t2 / Co;
    float a = 0.f;
    #pragma unroll
    for (int ky = 0; ky < 4; ++ky) {
        int ty = oy + 1 - ky;
        if (ty & 1) continue;
        int iy = ty >> 1;
        if (iy < 0 || iy >= S) continue;
        #pragma unroll
        for (int kx = 0; kx < 4; ++kx) {
            int tx = ox + 1 - kx;
            if (tx & 1) continue;
            int ix = tx >> 1;
            if (ix < 0 || ix >= S) continue;
            const float* ip = in + ((size_t)b * Ci * S + iy) * S + ix;
            const float* wp = w + co * 16 + ky * 4 + kx;
            #pragma unroll 4
            for (int ci = 0; ci < Ci; ++ci)
                a += ip[(size_t)ci * S * S] * wp[(size_t)ci * Co * 16];
        }
    }
    out[idx] = TANH ? tanhf(a) : a;
}

// ---------------------------------------------------------------------------
extern "C" void kernel_launch(void* const* d_in, const int* in_sizes, int n_in,
                              void* d_out, int out_size, void* d_ws, size_t ws_size,
                              hipStream_t stream)
{
    const float* x       = (const float*)d_in[0];
    const float* conv1_w = (const float*)d_in[1];
    const float* conv1_b = (const float*)d_in[2];
    const float* prim_w  = (const float*)d_in[3];
    const float* prim_b  = (const float*)d_in[4];
    const float* route_w = (const float*)d_in[5];
    const float* g1_w    = (const float*)d_in[6];
    const float* g2_w    = (const float*)d_in[7];
    const float* g3_w    = (const float*)d_in[8];
    const float* g4_w    = (const float*)d_in[9];
    const float* bn1_g   = (const float*)d_in[10];
    const float* bn1_b   = (const float*)d_in[11];
    const float* bn2_g   = (const float*)d_in[12];
    const float* bn2_b   = (const float*)d_in[13];
    const float* bn3_g   = (const float*)d_in[14];
    const float* bn3_b   = (const float*)d_in[15];
    float* outf = (float*)d_out;

    // ws layout (floats), lifetime-aliased (offsets unchanged from R5-R10):
    float* ws = (float*)d_ws;
    float* h      = ws;
    float* wt     = h + 19660800;
    float* part   = wt + 15925248;
    float* logits = wt;
    float* ut     = wt + 5242880;
    float* mbuf   = part;               // 1280
    float* sebuf  = part + 1280;        // 1280
    float* vbuf   = part + 2560;        // 20480
    float* zbuf   = part + 23040;       // 20480
    float* bnsc   = part + 64000;       // 896
    float* t1b    = part + 64896;       // 524288
    float* t2b    = part + 589184;      // 1048576
    float* t3b    = part + 1637760;     // 2097152  -> ends 3734912
    float* spart  = part + 4194304;     // 2621440  -> ends 6815744

    // stem + primary capsules
    primw_transpose_kernel<<<dim3(2048), 128, 0, stream>>>(prim_w, wt);
    conv1_kernel<<<dim3(128, 32), 192, 0, stream>>>(x, conv1_w, conv1_b, h);
    prim_conv_kernel<<<dim3(64, 8, 2), 256, 0, stream>>>(h, wt, part);
    squash_u_kernel<<<dim3(128, 16), 256, 0, stream>>>(part, prim_b, ut);

    // dynamic routing (3 iterations), deterministic two-stage reduction
    hipMemsetAsync(logits, 0, (size_t)5242880 * sizeof(float), stream);
    for (int it = 0; it < 3; ++it) {
        softmax_stats_kernel<<<dim3(1280), 256, 0, stream>>>(logits, mbuf, sebuf);
        route_s_kernel<<<dim3(10, 128), 256, 0, stream>>>(logits, ut, route_w, mbuf, sebuf, spart);
        route_v_kernel<<<dim3(20), 64, 0, stream>>>(spart, vbuf);
        if (it < 2)
            route_upd_kernel<<<dim3(10, 128), 256, 0, stream>>>(logits, ut, route_w, vbuf);
    }
    caps_out_kernel<<<dim3(1), 128, 0, stream>>>(vbuf, outf, zbuf);

    // generator
    gen1_kernel<<<dim3(2048), 256, 0, stream>>>(zbuf, g1_w, t1b);
    bn_stats_kernel<256, 16><<<dim3(256), 256, 0, stream>>>(t1b, bn1_g, bn1_b, bnsc, bnsc + 256);
    bn_apply_kernel<256, 16><<<dim3(2048), 256, 0, stream>>>(t1b, bnsc, bnsc + 256, 524288);

    deconv_row_kernel<256, 128, 4, 4><<<dim3(128, 4), 256, 0, stream>>>(t1b, g2_w, t2b);
    bn_stats_kernel<128, 64><<<dim3(128), 256, 0, stream>>>(t2b, bn2_g, bn2_b, bnsc + 512, bnsc + 640);
    bn_apply_kernel<128, 64><<<dim3(4096), 256, 0, stream>>>(t2b, bnsc + 512, bnsc + 640, 1048576);

    deconv_row_kernel<128, 64, 8, 4><<<dim3(128, 4), 256, 0, stream>>>(t2b, g3_w, t3b);
    bn_stats_kernel<64, 256><<<dim3(64), 256, 0, stream>>>(t3b, bn3_g, bn3_b, bnsc + 768, bnsc + 832);
    bn_apply_kernel<64, 256><<<dim3(8192), 256, 0, stream>>>(t3b, bnsc + 768, bnsc + 832, 2097152);

    deconv_kernel<64, 3, 16, true><<<dim3(1536), 256, 0, stream>>>(t3b, g4_w, outf + 1280);
}

// Round 12
// 3746.781 us; speedup vs baseline: 1.0971x; 1.0971x over previous
//
#include <hip/hip_runtime.h>
#include <cmath>

#define NB 128  // batch

#define H_STRIDE 600     // floats per (b,ci) h plane: 24 rows x 25 pad
#define W_SLAB   5184    // floats per (g,ci) wt slab: 81 taps x 64 ch (split-half layout)

// ---------------------------------------------------------------------------
// conv1: x[128,3,32,32] -> h[128,256,(24x25 pad)] = relu(conv(x,w)+bias)
// ---------------------------------------------------------------------------
__global__ __launch_bounds__(192) void conv1_kernel(
    const float* __restrict__ x, const float* __restrict__ w,
    const float* __restrict__ bias, float* __restrict__ h)
{
    __shared__ float4 xs4[768];              // 3*32*32 floats
    float* xs = (float*)xs4;
    int b = blockIdx.x, cobase = blockIdx.y * 8, tid = threadIdx.x;
    const float4* xsrc = (const float4*)(x + (size_t)b * 3072);
    for (int i = tid; i < 768; i += 192) xs4[i] = xsrc[i];
    __syncthreads();
    for (int round = 0; round < 3; ++round) {
        int px = round * 192 + tid;          // 0..575
        int yy = px / 24, xx = px - yy * 24;
        float acc[8];
        #pragma unroll
        for (int cc = 0; cc < 8; ++cc) acc[cc] = 0.f;
        for (int c = 0; c < 3; ++c)
            for (int ky = 0; ky < 9; ++ky) {
                const float* xr = xs + c * 1024 + (yy + ky) * 32 + xx;
                float xv[9];
                #pragma unroll
                for (int kx = 0; kx < 9; ++kx) xv[kx] = xr[kx];
                int tb = c * 81 + ky * 9;
                #pragma unroll
                for (int cc = 0; cc < 8; ++cc) {
                    const float* wp = w + (cobase + cc) * 243 + tb;  // wave-uniform -> s_load
                    #pragma unroll
                    for (int kx = 0; kx < 9; ++kx) acc[cc] += xv[kx] * wp[kx];
                }
            }
        #pragma unroll
        for (int cc = 0; cc < 8; ++cc)
            h[((size_t)b * 256 + cobase + cc) * H_STRIDE + yy * 25 + xx] =
                fmaxf(acc[cc] + bias[cobase + cc], 0.f);
    }
}

// ---------------------------------------------------------------------------
// prim weight transpose: prim_w[512,256,81] -> wt[g][ci][tap][64] split-half:
//   ch = q*4 + r (q=0..15): r<2 -> tap*64 + 2q + r ; r>=2 -> tap*64 + 32 + 2q + (r-2)
// Both sides coalesced via LDS tile buf[64][82].
// ---------------------------------------------------------------------------
__global__ __launch_bounds__(128) void primw_transpose_kernel(
    const float* __restrict__ pw, float* __restrict__ wt)
{
    __shared__ float buf[64 * 82];           // 21 KB
    int g = blockIdx.x >> 8, ci = blockIdx.x & 255, tid = threadIdx.x;
    for (int idx = tid; idx < 5184; idx += 128) {
        int ch = idx / 81, t = idx - ch * 81;
        buf[ch * 82 + t] = pw[((size_t)(g * 64 + ch) * 256 + ci) * 81 + t];
    }
    __syncthreads();
    float* dst = wt + (size_t)(g * 256 + ci) * W_SLAB;
    for (int f = tid; f < W_SLAB; f += 128) {
        int tap = f >> 6;
        int rem = f & 63;
        int half = rem >> 5;                 // 0 = lo pair, 1 = hi pair
        int e = rem & 31;
        int q = e >> 1, j = e & 1;
        int ch = q * 4 + half * 2 + j;
        dst[f] = buf[ch * 82 + tap];
    }
}

// ---------------------------------------------------------------------------
// primary capsules (R9-proven): 2 images per block, single-buffered staging.
// grid (64 b2, 8 g, 2 half), 256 thr; waves 0-1 -> img 0, 2-3 -> img 1;
// each thread 4ch x 8px. w read = 2x ds_read_b64, conflict-free split-half.
// part[((half*128+b)*8+g)*4096 + c64*64+px]
// ---------------------------------------------------------------------------
__global__ __launch_bounds__(256) void prim_conv_kernel(
    const float* __restrict__ h, const float* __restrict__ wt,
    float* __restrict__ part)
{
    __shared__ __align__(16) float wsh[W_SLAB];        // 5184 floats
    __shared__ __align__(16) float hsh[2 * H_STRIDE];  // 1200 floats
    int b2 = blockIdx.x, g = blockIdx.y, half = blockIdx.z, tid = threadIdx.x;
    int ci0 = half * 128;
    int img = tid >> 7;              // 0..1 (wave-uniform)
    int t128 = tid & 127;
    int quad = t128 & 15;            // 4-channel group: ch = quad*4 .. quad*4+3
    int prow = t128 >> 4;            // output row 0..7 (8 px)
    int b = b2 * 2 + img;
    int hbase = img * H_STRIDE;
    int wlo = 2 * quad;              // lo-pair offset within tap record
    int whi = 32 + 2 * quad;         // hi-pair offset

    float acc[4][8];
    #pragma unroll
    for (int i = 0; i < 4; ++i)
        #pragma unroll
        for (int j = 0; j < 8; ++j) acc[i][j] = 0.f;

    #define STAGE(ci)                                                                        \
    {                                                                                        \
        const float* wsrc = wt + (size_t)(g * 256 + (ci)) * W_SLAB;                          \
        const float* h0src = h + ((size_t)(b2 * 2 + 0) * 256 + (ci)) * H_STRIDE;             \
        const float* h1src = h + ((size_t)(b2 * 2 + 1) * 256 + (ci)) * H_STRIDE;             \
        _Pragma("unroll")                                                                    \
        for (int k = 0; k < 6; ++k) {                                                        \
            int ix = k * 256 + tid;                                                          \
            if (ix < 1296)                                                                   \
                __builtin_amdgcn_global_load_lds(                                            \
                    (const unsigned int*)wsrc + ix * 4,                                      \
                    (unsigned int*)wsh + ix * 4, 16, 0, 0);                                  \
        }                                                                                    \
        if (tid < 150)                                                                       \
            __builtin_amdgcn_global_load_lds(                                                \
                (const unsigned int*)h0src + tid * 4,                                        \
                (unsigned int*)hsh + tid * 4, 16, 0, 0);                                     \
        if (tid < 150)                                                                       \
            __builtin_amdgcn_global_load_lds(                                                \
                (const unsigned int*)h1src + tid * 4,                                        \
                (unsigned int*)(hsh + H_STRIDE) + tid * 4, 16, 0, 0);                        \
    }

    STAGE(ci0);
    asm volatile("s_waitcnt vmcnt(0)" ::: "memory");
    __syncthreads();

    for (int ci = ci0; ci < ci0 + 128; ++ci) {
        #pragma unroll 3
        for (int ky = 0; ky < 9; ++ky) {
            int hr = hbase + (2 * prow + ky) * 25;
            float hv[23];
            #pragma unroll
            for (int t = 0; t < 23; ++t) hv[t] = hsh[hr + t];
            #pragma unroll
            for (int kx = 0; kx < 9; ++kx) {
                const float* wp = wsh + (ky * 9 + kx) * 64;
                float2 wa = *(const float2*)(wp + wlo);
                float2 wb = *(const float2*)(wp + whi);
                float wv[4] = {wa.x, wa.y, wb.x, wb.y};
                #pragma unroll
                for (int j = 0; j < 8; ++j) {
                    float hx = hv[2 * j + kx];
                    #pragma unroll
                    for (int i = 0; i < 4; ++i) acc[i][j] += wv[i] * hx;
                }
            }
        }
        __syncthreads();                          // all waves done reading LDS
        if (ci + 1 < ci0 + 128) STAGE(ci + 1);    // overwrite
        asm volatile("s_waitcnt vmcnt(0)" ::: "memory");
        __syncthreads();                          // staged data visible to all
    }
    #undef STAGE

    float* pp = part + ((size_t)(half * 128 + b) * 8 + g) * 4096;
    #pragma unroll
    for (int i = 0; i < 4; ++i) {
        int c64 = quad * 4 + i;
        *(float4*)(pp + c64 * 64 + prow * 8) =
            make_float4(acc[i][0], acc[i][1], acc[i][2], acc[i][3]);
        *(float4*)(pp + c64 * 64 + prow * 8 + 4) =
            make_float4(acc[i][4], acc[i][5], acc[i][6], acc[i][7]);
    }
}

// ---------------------------------------------------------------------------
// combine halves + bias + squash over capsule dim -> ut[b][r][8]
// ---------------------------------------------------------------------------
__global__ void squash_u_kernel(const float* __restrict__ part,
                                const float* __restrict__ pb, float* __restrict__ ut)
{
    int b = blockIdx.x; int r = blockIdx.y * 256 + threadIdx.x;
    int c64 = r >> 6;
    const float* p0 = part + (size_t)b * 8 * 4096 + r;
    const float* p1 = part + (size_t)(128 + b) * 8 * 4096 + r;
    float v[8]; float sq = 0.f;
    #pragma unroll
    for (int i = 0; i < 8; ++i) {
        v[i] = p0[(size_t)i * 4096] + p1[(size_t)i * 4096] + pb[i * 64 + c64];
        sq += v[i] * v[i];
    }
    float sc = sqrtf(sq) / (1.f + sq);
    float4 o0 = make_float4(v[0] * sc, v[1] * sc, v[2] * sc, v[3] * sc);
    float4 o1 = make_float4(v[4] * sc, v[5] * sc, v[6] * sc, v[7] * sc);
    float* o = ut + ((size_t)b * 4096 + r) * 8;
    *(float4*)o = o0; *(float4*)(o + 4) = o1;
}

// ---------------------------------------------------------------------------
// softmax stats over r (4096) per (c,b) row of logits
// ---------------------------------------------------------------------------
__global__ void softmax_stats_kernel(const float* __restrict__ logits,
                                     float* __restrict__ mbuf, float* __restrict__ sebuf)
{
    int cb = blockIdx.x; int tid = threadIdx.x;
    const float* lrow = logits + (size_t)cb * 4096;
    float mx = -1e30f;
    for (int i = tid; i < 4096; i += 256) mx = fmaxf(mx, lrow[i]);
    #pragma unroll
    for (int d = 1; d < 64; d <<= 1) mx = fmaxf(mx, __shfl_xor(mx, d));
    __shared__ float rm[4], rs[4];
    if ((tid & 63) == 0) rm[tid >> 6] = mx;
    __syncthreads();
    mx = fmaxf(fmaxf(rm[0], rm[1]), fmaxf(rm[2], rm[3]));
    float s = 0.f;
    for (int i = tid; i < 4096; i += 256) s += expf(lrow[i] - mx);
    #pragma unroll
    for (int d = 1; d < 64; d <<= 1) s += __shfl_xor(s, d);
    if ((tid & 63) == 0) rs[tid >> 6] = s;
    __syncthreads();
    if (tid == 0) {
        mbuf[cb] = mx;
        sebuf[cb] = rs[0] + rs[1] + rs[2] + rs[3];
    }
}

// ---------------------------------------------------------------------------
// routing phase A (R5-proven): per (c, 32-r chunk) partial s, deterministic
// ---------------------------------------------------------------------------
__global__ __launch_bounds__(256) void route_s_kernel(
    const float* __restrict__ logits, const float* __restrict__ ut,
    const float* __restrict__ route_w, const float* __restrict__ mbuf,
    const float* __restrict__ sebuf, float* __restrict__ spart)
{
    __shared__ __align__(16) float smem[11232];
    const int UB = 4224, PB = 8400, RB = 8928;
    int c = blockIdx.x, ch = blockIdx.y, tid = threadIdx.x;
    int r0 = ch * 32;

    {
        const float4* w4 = (const float4*)(route_w + ((size_t)c * 4096 + r0) * 128);
        #pragma unroll
        for (int k = 0; k < 4; ++k) {
            int idx = k * 256 + tid;
            float4 wv = w4[idx];
            int rl = idx >> 5, rem = (idx & 31) * 4;
            *(float4*)(smem + rl * 132 + rem) = wv;
        }
    }

    int bC = tid & 15, igC = (tid >> 4) & 7, ohC = tid >> 7;

    for (int bg = 0; bg < 8; ++bg) {
        int b0 = bg * 16;
        __syncthreads();
        {
            int bb = tid >> 4, seg = tid & 15;
            const float4* us = (const float4*)(ut + (size_t)(b0 + bb) * 32768 + (size_t)r0 * 8);
            #pragma unroll
            for (int q = 0; q < 4; ++q) {
                float4 v = us[seg * 4 + q];
                int base = UB + bb * 261 + (seg * 4 + q) * 4;
                smem[base + 0] = v.x; smem[base + 1] = v.y;
                smem[base + 2] = v.z; smem[base + 3] = v.w;
            }
        }
        if (tid < 128) {
            int b = tid >> 3, rr = tid & 7;
            int cb = c * 128 + b0 + b;
            float m = mbuf[cb];
            float inv = 1.0f / sebuf[cb];
            float4 lv = *(const float4*)(logits + (size_t)cb * 4096 + r0 + rr * 4);
            int pbb = PB + b * 33 + rr * 4;
            smem[pbb + 0] = expf(lv.x - m) * inv;
            smem[pbb + 1] = expf(lv.y - m) * inv;
            smem[pbb + 2] = expf(lv.z - m) * inv;
            smem[pbb + 3] = expf(lv.w - m) * inv;
        }
        __syncthreads();
        float4 a0 = make_float4(0.f, 0.f, 0.f, 0.f);
        float4 a1 = make_float4(0.f, 0.f, 0.f, 0.f);
        int ub = UB + bC * 261 + igC;
        int wb = igC * 16 + ohC * 8;
        int pbb = PB + bC * 33;
        for (int rl = 0; rl < 32; ++rl) {
            float uu = smem[ub + rl * 8];
            float pr = smem[pbb + rl];
            float t1 = pr * uu;
            const float* wp = smem + rl * 132 + wb;
            float4 w0 = *(const float4*)wp;
            float4 w1 = *(const float4*)(wp + 4);
            a0.x += t1 * w0.x; a0.y += t1 * w0.y; a0.z += t1 * w0.z; a0.w += t1 * w0.w;
            a1.x += t1 * w1.x; a1.y += t1 * w1.y; a1.z += t1 * w1.z; a1.w += t1 * w1.w;
        }
        int rb = RB + tid * 9;
        smem[rb + 0] = a0.x; smem[rb + 1] = a0.y; smem[rb + 2] = a0.z; smem[rb + 3] = a0.w;
        smem[rb + 4] = a1.x; smem[rb + 5] = a1.y; smem[rb + 6] = a1.z; smem[rb + 7] = a1.w;
        __syncthreads();
        {
            int o = tid & 15, b = tid >> 4;
            int oh = o >> 3, ol = o & 7;
            float s = 0.f;
            #pragma unroll
            for (int ig = 0; ig < 8; ++ig)
                s += smem[RB + (b + 16 * ig + 128 * oh) * 9 + ol];
            spart[(size_t)ch * 20480 + (size_t)(c * 128 + b0 + b) * 16 + o] = s;
        }
    }
}

// ---------------------------------------------------------------------------
// routing phase B: s = sum_ch spart (fixed order), v = squash(s) per (c,b)
// ---------------------------------------------------------------------------
__global__ void route_v_kernel(const float* __restrict__ spart, float* __restrict__ vbuf)
{
    int cb = blockIdx.x * 64 + threadIdx.x;  // 1280
    float4 a0 = make_float4(0,0,0,0), a1 = make_float4(0,0,0,0);
    float4 a2 = make_float4(0,0,0,0), a3 = make_float4(0,0,0,0);
    for (int k = 0; k < 128; ++k) {
        const float4* p = (const float4*)(spart + (size_t)k * 20480 + (size_t)cb * 16);
        float4 b0 = p[0], b1 = p[1], b2 = p[2], b3 = p[3];
        a0.x += b0.x; a0.y += b0.y; a0.z += b0.z; a0.w += b0.w;
        a1.x += b1.x; a1.y += b1.y; a1.z += b1.z; a1.w += b1.w;
        a2.x += b2.x; a2.y += b2.y; a2.z += b2.z; a2.w += b2.w;
        a3.x += b3.x; a3.y += b3.y; a3.z += b3.z; a3.w += b3.w;
    }
    float sq = a0.x*a0.x + a0.y*a0.y + a0.z*a0.z + a0.w*a0.w
             + a1.x*a1.x + a1.y*a1.y + a1.z*a1.z + a1.w*a1.w
             + a2.x*a2.x + a2.y*a2.y + a2.z*a2.z + a2.w*a2.w
             + a3.x*a3.x + a3.y*a3.y + a3.z*a3.z + a3.w*a3.w;
    float sc = sqrtf(sq) / (1.f + sq);
    float4* vp = (float4*)(vbuf + (size_t)cb * 16);
    vp[0] = make_float4(a0.x*sc, a0.y*sc, a0.z*sc, a0.w*sc);
    vp[1] = make_float4(a1.x*sc, a1.y*sc, a1.z*sc, a1.w*sc);
    vp[2] = make_float4(a2.x*sc, a2.y*sc, a2.z*sc, a2.w*sc);
    vp[3] = make_float4(a3.x*sc, a3.y*sc, a3.z*sc, a3.w*sc);
}

// ---------------------------------------------------------------------------
// routing phase C (R5-proven): logits += prior . v
// ---------------------------------------------------------------------------
__global__ __launch_bounds__(256) void route_upd_kernel(
    float* __restrict__ logits, const float* __restrict__ ut,
    const float* __restrict__ route_w, const float* __restrict__ vbuf)
{
    __shared__ __align__(16) float smem[8400];   // wch 4224 + ubuf 4176
    const int UB = 4224;
    int c = blockIdx.x, ch = blockIdx.y, tid = threadIdx.x;
    int r0 = ch * 32;
    {
        const float4* w4 = (const float4*)(route_w + ((size_t)c * 4096 + r0) * 128);
        #pragma unroll
        for (int k = 0; k < 4; ++k) {
            int idx = k * 256 + tid;
            float4 wv = w4[idx];
            int rl = idx >> 5, rem = (idx & 31) * 4;
            *(float4*)(smem + rl * 132 + rem) = wv;
        }
    }
    int b = tid & 15, rg = tid >> 4;
    for (int bg = 0; bg < 8; ++bg) {
        int b0 = bg * 16;
        __syncthreads();
        {
            int bb = tid >> 4, seg = tid & 15;
            const float4* us = (const float4*)(ut + (size_t)(b0 + bb) * 32768 + (size_t)r0 * 8);
            #pragma unroll
            for (int q = 0; q < 4; ++q) {
                float4 v = us[seg * 4 + q];
                int base = UB + bb * 261 + (seg * 4 + q) * 4;
                smem[base + 0] = v.x; smem[base + 1] = v.y;
                smem[base + 2] = v.z; smem[base + 3] = v.w;
            }
        }
        __syncthreads();
        int cb = c * 128 + b0 + b;
        const float4* vp = (const float4*)(vbuf + (size_t)cb * 16);
        float4 v0 = vp[0], v1 = vp[1], v2 = vp[2], v3 = vp[3];
        #pragma unroll
        for (int jj = 0; jj < 2; ++jj) {
            int rl = rg * 2 + jj;
            float4 p0 = make_float4(0,0,0,0), p1 = make_float4(0,0,0,0);
            float4 p2 = make_float4(0,0,0,0), p3 = make_float4(0,0,0,0);
            int ub = UB + b * 261 + rl * 8;
            #pragma unroll
            for (int i = 0; i < 8; ++i) {
                float uu = smem[ub + i];
                const float* wp = smem + rl * 132 + i * 16;
                float4 w0 = *(const float4*)wp;
                float4 w1 = *(const float4*)(wp + 4);
                float4 w2 = *(const float4*)(wp + 8);
                float4 w3 = *(const float4*)(wp + 12);
                p0.x += uu*w0.x; p0.y += uu*w0.y; p0.z += uu*w0.z; p0.w += uu*w0.w;
                p1.x += uu*w1.x; p1.y += uu*w1.y; p1.z += uu*w1.z; p1.w += uu*w1.w;
                p2.x += uu*w2.x; p2.y += uu*w2.y; p2.z += uu*w2.z; p2.w += uu*w2.w;
                p3.x += uu*w3.x; p3.y += uu*w3.y; p3.z += uu*w3.z; p3.w += uu*w3.w;
            }
            float delta = p0.x*v0.x + p0.y*v0.y + p0.z*v0.z + p0.w*v0.w
                        + p1.x*v1.x + p1.y*v1.y + p1.z*v1.z + p1.w*v1.w
                        + p2.x*v2.x + p2.y*v2.y + p2.z*v2.z + p2.w*v2.w
                        + p3.x*v3.x + p3.y*v3.y + p3.z*v3.z + p3.w*v3.w;
            logits[(size_t)cb * 4096 + r0 + rl] += delta;
        }
    }
}

// ---------------------------------------------------------------------------
// classes softmax + argmax one-hot mask -> z
// ---------------------------------------------------------------------------
__global__ void caps_out_kernel(const float* __restrict__ vbuf,
                                float* __restrict__ out_classes, float* __restrict__ zbuf)
{
    int b = threadIdx.x;  // 128
    float norms[10];
    #pragma unroll
    for (int c = 0; c < 10; ++c) {
        const float* vp = vbuf + (size_t)(c * 128 + b) * 16;
        float sq = 0.f;
        #pragma unroll
        for (int o = 0; o < 16; ++o) sq += vp[o] * vp[o];
        norms[c] = sqrtf(sq);
    }
    float mx = norms[0]; int am = 0;
    #pragma unroll
    for (int c = 1; c < 10; ++c) if (norms[c] > mx) { mx = norms[c]; am = c; }
    float se = 0.f; float e[10];
    #pragma unroll
    for (int c = 0; c < 10; ++c) { e[c] = expf(norms[c] - mx); se += e[c]; }
    float isd = 1.f / se;
    #pragma unroll
    for (int c = 0; c < 10; ++c) out_classes[b * 10 + c] = e[c] * isd;
    #pragma unroll
    for (int c = 0; c < 10; ++c) {
        const float* vp = vbuf + (size_t)(c * 128 + b) * 16;
        #pragma unroll
        for (int o = 0; o < 16; ++o)
            zbuf[b * 160 + c * 16 + o] = (c == am) ? vp[o] : 0.f;
    }
}

// ---------------------------------------------------------------------------
// generator stage 1: z[128,160] x g1_w[160,256*16] -> t1[128,4096] (raw)
// ---------------------------------------------------------------------------
__global__ void gen1_kernel(const float* __restrict__ z, const float* __restrict__ w,
                            float* __restrict__ out)
{
    int idx = blockIdx.x * 256 + threadIdx.x;  // 524288
    int j = idx & 4095; int b = idx >> 12;
    const float* zp = z + b * 160;
    float a = 0.f;
    #pragma unroll 4
    for (int ci = 0; ci < 160; ++ci) a += zp[ci] * w[(size_t)ci * 4096 + j];
    out[idx] = a;
}

// ---------------------------------------------------------------------------
// batchnorm stats (training-mode) per channel over (N,H,W) of RAW tensor
// ---------------------------------------------------------------------------
template <int C, int HW>
__global__ void bn_stats_kernel(const float* __restrict__ t, const float* __restrict__ g,
                                const float* __restrict__ beta,
                                float* __restrict__ scale, float* __restrict__ shift)
{
    int co = blockIdx.x; int tid = threadIdx.x;
    float s = 0.f, s2 = 0.f;
    for (int i = tid; i < NB * HW; i += 256) {
        int b = i / HW, hw = i - b * HW;
        float v = t[((size_t)b * C + co) * HW + hw];
        s += v; s2 += v * v;
    }
    #pragma unroll
    for (int d = 1; d < 64; d <<= 1) { s += __shfl_xor(s, d); s2 += __shfl_xor(s2, d); }
    __shared__ float rs[4], rs2[4];
    if ((tid & 63) == 0) { rs[tid >> 6] = s; rs2[tid >> 6] = s2; }
    __syncthreads();
    if (tid == 0) {
        float S = rs[0] + rs[1] + rs[2] + rs[3];
        float S2 = rs2[0] + rs2[1] + rs2[2] + rs2[3];
        const float n = (float)(NB * HW);
        float mean = S / n;
        float var = S2 / n - mean * mean;
        float r = 1.f / sqrtf(var + 1e-5f);
        scale[co] = g[co] * r;
        shift[co] = beta[co] - mean * g[co] * r;
    }
}

// ---------------------------------------------------------------------------
// LDS-staged transposed conv (k=4,s=2,p=1): thread owns one (co,oy) row.
// BN: apply relu(in*scale+shift) while staging input (fused bn_apply).
// TANH: apply tanh to outputs (final stage).
// ---------------------------------------------------------------------------
template <int Ci, int Co, int S, int SPLIT, bool BN, bool TANH>
__global__ __launch_bounds__(256) void deconv_row_kernel(
    const float* __restrict__ in, const float* __restrict__ w,
    const float* __restrict__ scale, const float* __restrict__ shift,
    float* __restrict__ out)
{
    constexpr int OS = 2 * S;
    constexpr int ROWS = Co * OS;
    constexpr int RPB = ROWS / SPLIT;
    __shared__ __align__(16) float ish[Ci * S * S];
    int b = blockIdx.x, rb = blockIdx.y, tid = threadIdx.x;
    const float4* src = (const float4*)(in + (size_t)b * Ci * S * S);
    for (int i = tid; i < Ci * S * S / 4; i += 256) {
        float4 v = src[i];
        if (BN) {
            int cin = (i * 4) / (S * S);
            float sc = scale[cin], sh = shift[cin];
            v.x = fmaxf(v.x * sc + sh, 0.f);
            v.y = fmaxf(v.y * sc + sh, 0.f);
            v.z = fmaxf(v.z * sc + sh, 0.f);
            v.w = fmaxf(v.w * sc + sh, 0.f);
        }
        ((float4*)ish)[i] = v;
    }
    __syncthreads();

    for (int r = rb * RPB + tid; r < (rb + 1) * RPB; r += 256) {
        int co = r / OS, oy = r % OS;
        float acc[OS];
        #pragma unroll
        for (int j = 0; j < OS; ++j) acc[j] = 0.f;
        int p = (oy + 1) & 1;                      // ky parity
        for (int ci = 0; ci < Ci; ++ci) {
            const float* wci = w + ((size_t)ci * Co + co) * 16;
            #pragma unroll
            for (int t = 0; t < 2; ++t) {
                int ky = p + 2 * t;
                int iy = (oy + 1 - ky) >> 1;       // exact (even numerator)
                if (iy < 0 || iy >= S) continue;
                float4 wv = *(const float4*)(wci + ky * 4);
                const float* irow = ish + (ci * S + iy) * S;
                #pragma unroll
                for (int ox = 0; ox < OS; ++ox) {
                    int q = (ox + 1) & 1;
                    int ix0 = (ox + 1 - q) >> 1;   // kx = q
                    int ix1 = ix0 - 1;             // kx = q+2
                    float wk0 = q ? wv.y : wv.x;
                    float wk2 = q ? wv.w : wv.z;
                    if (ix0 < S)  acc[ox] += wk0 * irow[ix0];
                    if (ix1 >= 0) acc[ox] += wk2 * irow[ix1];
                }
            }
        }
        if (TANH) {
            #pragma unroll
            for (int j = 0; j < OS; ++j) acc[j] = tanhf(acc[j]);
        }
        float* orow = out + ((size_t)(b * Co + co) * OS + oy) * OS;
        #pragma unroll
        for (int j = 0; j < OS; j += 4)
            *(float4*)(orow + j) = make_float4(acc[j], acc[j+1], acc[j+2], acc[j+3]);
    }
}

// ---------------------------------------------------------------------------
extern "C" void kernel_launch(void* const* d_in, const int* in_sizes, int n_in,
                              void* d_out, int out_size, void* d_ws, size_t ws_size,
                              hipStream_t stream)
{
    const float* x       = (const float*)d_in[0];
    const float* conv1_w = (const float*)d_in[1];
    const float* conv1_b = (const float*)d_in[2];
    const float* prim_w  = (const float*)d_in[3];
    const float* prim_b  = (const float*)d_in[4];
    const float* route_w = (const float*)d_in[5];
    const float* g1_w    = (const float*)d_in[6];
    const float* g2_w    = (const float*)d_in[7];
    const float* g3_w    = (const float*)d_in[8];
    const float* g4_w    = (const float*)d_in[9];
    const float* bn1_g   = (const float*)d_in[10];
    const float* bn1_b   = (const float*)d_in[11];
    const float* bn2_g   = (const float*)d_in[12];
    const float* bn2_b   = (const float*)d_in[13];
    const float* bn3_g   = (const float*)d_in[14];
    const float* bn3_b   = (const float*)d_in[15];
    float* outf = (float*)d_out;

    // ws layout (floats), lifetime-aliased (offsets unchanged from R5-R10):
    float* ws = (float*)d_ws;
    float* h      = ws;
    float* wt     = h + 19660800;
    float* part   = wt + 15925248;
    float* logits = wt;
    float* ut     = wt + 5242880;
    float* mbuf   = part;               // 1280
    float* sebuf  = part + 1280;        // 1280
    float* vbuf   = part + 2560;        // 20480
    float* zbuf   = part + 23040;       // 20480
    float* bnsc   = part + 64000;       // 896
    float* t1b    = part + 64896;       // 524288
    float* t2b    = part + 589184;      // 1048576
    float* t3b    = part + 1637760;     // 2097152  -> ends 3734912
    float* spart  = part + 4194304;     // 2621440  -> ends 6815744

    // stem + primary capsules
    primw_transpose_kernel<<<dim3(2048), 128, 0, stream>>>(prim_w, wt);
    conv1_kernel<<<dim3(128, 32), 192, 0, stream>>>(x, conv1_w, conv1_b, h);
    prim_conv_kernel<<<dim3(64, 8, 2), 256, 0, stream>>>(h, wt, part);
    squash_u_kernel<<<dim3(128, 16), 256, 0, stream>>>(part, prim_b, ut);

    // dynamic routing (3 iterations), deterministic two-stage reduction
    hipMemsetAsync(logits, 0, (size_t)5242880 * sizeof(float), stream);
    for (int it = 0; it < 3; ++it) {
        softmax_stats_kernel<<<dim3(1280), 256, 0, stream>>>(logits, mbuf, sebuf);
        route_s_kernel<<<dim3(10, 128), 256, 0, stream>>>(logits, ut, route_w, mbuf, sebuf, spart);
        route_v_kernel<<<dim3(20), 64, 0, stream>>>(spart, vbuf);
        if (it < 2)
            route_upd_kernel<<<dim3(10, 128), 256, 0, stream>>>(logits, ut, route_w, vbuf);
    }
    caps_out_kernel<<<dim3(1), 128, 0, stream>>>(vbuf, outf, zbuf);

    // generator: raw deconv outputs in t-buffers; BN+ReLU fused into next stage
    gen1_kernel<<<dim3(2048), 256, 0, stream>>>(zbuf, g1_w, t1b);
    bn_stats_kernel<256, 16><<<dim3(256), 256, 0, stream>>>(t1b, bn1_g, bn1_b, bnsc, bnsc + 256);

    deconv_row_kernel<256, 128, 4, 4, true, false>
        <<<dim3(128, 4), 256, 0, stream>>>(t1b, g2_w, bnsc, bnsc + 256, t2b);
    bn_stats_kernel<128, 64><<<dim3(128), 256, 0, stream>>>(t2b, bn2_g, bn2_b, bnsc + 512, bnsc + 640);

    deconv_row_kernel<128, 64, 8, 4, true, false>
        <<<dim3(128, 4), 256, 0, stream>>>(t2b, g3_w, bnsc + 512, bnsc + 640, t3b);
    bn_stats_kernel<64, 256><<<dim3(64), 256, 0, stream>>>(t3b, bn3_g, bn3_b, bnsc + 768, bnsc + 832);

    deconv_row_kernel<64, 3, 16, 1, true, true>
        <<<dim3(128, 1), 256, 0, stream>>>(t3b, g4_w, bnsc + 768, bnsc + 832, outf + 1280);
}

// Round 13
// 3697.165 us; speedup vs baseline: 1.1118x; 1.0134x over previous
//
#include <hip/hip_runtime.h>
#include <cmath>

#define NB 128  // batch

#define H_STRIDE 600     // floats per (b,ci) h plane: 24 rows x 25 pad
#define W_SLAB   5184    // floats per (g,ci) wt slab: 81 taps x 64 ch (split-half layout)

// ---------------------------------------------------------------------------
// conv1: x[128,3,32,32] -> h[128,256,(24x25 pad)] = relu(conv(x,w)+bias)
// ---------------------------------------------------------------------------
__global__ __launch_bounds__(192) void conv1_kernel(
    const float* __restrict__ x, const float* __restrict__ w,
    const float* __restrict__ bias, float* __restrict__ h)
{
    __shared__ float4 xs4[768];              // 3*32*32 floats
    float* xs = (float*)xs4;
    int b = blockIdx.x, cobase = blockIdx.y * 8, tid = threadIdx.x;
    const float4* xsrc = (const float4*)(x + (size_t)b * 3072);
    for (int i = tid; i < 768; i += 192) xs4[i] = xsrc[i];
    __syncthreads();
    for (int round = 0; round < 3; ++round) {
        int px = round * 192 + tid;          // 0..575
        int yy = px / 24, xx = px - yy * 24;
        float acc[8];
        #pragma unroll
        for (int cc = 0; cc < 8; ++cc) acc[cc] = 0.f;
        for (int c = 0; c < 3; ++c)
            for (int ky = 0; ky < 9; ++ky) {
                const float* xr = xs + c * 1024 + (yy + ky) * 32 + xx;
                float xv[9];
                #pragma unroll
                for (int kx = 0; kx < 9; ++kx) xv[kx] = xr[kx];
                int tb = c * 81 + ky * 9;
                #pragma unroll
                for (int cc = 0; cc < 8; ++cc) {
                    const float* wp = w + (cobase + cc) * 243 + tb;  // wave-uniform -> s_load
                    #pragma unroll
                    for (int kx = 0; kx < 9; ++kx) acc[cc] += xv[kx] * wp[kx];
                }
            }
        #pragma unroll
        for (int cc = 0; cc < 8; ++cc)
            h[((size_t)b * 256 + cobase + cc) * H_STRIDE + yy * 25 + xx] =
                fmaxf(acc[cc] + bias[cobase + cc], 0.f);
    }
}

// ---------------------------------------------------------------------------
// prim weight transpose: prim_w[512,256,81] -> wt[g][ci][tap][64] split-half:
//   ch = q*4 + r (q=0..15): r<2 -> tap*64 + 2q + r ; r>=2 -> tap*64 + 32 + 2q + (r-2)
// Both sides coalesced via LDS tile buf[64][82].
// ---------------------------------------------------------------------------
__global__ __launch_bounds__(128) void primw_transpose_kernel(
    const float* __restrict__ pw, float* __restrict__ wt)
{
    __shared__ float buf[64 * 82];           // 21 KB
    int g = blockIdx.x >> 8, ci = blockIdx.x & 255, tid = threadIdx.x;
    for (int idx = tid; idx < 5184; idx += 128) {
        int ch = idx / 81, t = idx - ch * 81;
        buf[ch * 82 + t] = pw[((size_t)(g * 64 + ch) * 256 + ci) * 81 + t];
    }
    __syncthreads();
    float* dst = wt + (size_t)(g * 256 + ci) * W_SLAB;
    for (int f = tid; f < W_SLAB; f += 128) {
        int tap = f >> 6;
        int rem = f & 63;
        int half = rem >> 5;                 // 0 = lo pair, 1 = hi pair
        int e = rem & 31;
        int q = e >> 1, j = e & 1;
        int ch = q * 4 + half * 2 + j;
        dst[f] = buf[ch * 82 + tap];
    }
}

// ---------------------------------------------------------------------------
// primary capsules (R9-proven body): 2 images per block, single-buffer stage.
// grid (64 b2, 8 g, 3 ci-third) = 1536 blocks -> 6 blocks/CU (24 waves/CU).
// waves 0-1 -> img 0, 2-3 -> img 1; each thread 4ch x 8px (one row).
// w read = 2x ds_read_b64, conflict-free split-half.
// part[((q*128+b)*8+g)*4096 + c64*64+px]
// ---------------------------------------------------------------------------
__global__ __launch_bounds__(256) void prim_conv_kernel(
    const float* __restrict__ h, const float* __restrict__ wt,
    float* __restrict__ part)
{
    __shared__ __align__(16) float wsh[W_SLAB];        // 5184 floats
    __shared__ __align__(16) float hsh[2 * H_STRIDE];  // 1200 floats
    int b2 = blockIdx.x, g = blockIdx.y, q = blockIdx.z, tid = threadIdx.x;
    int ci0 = (q * 256) / 3;                 // 0, 85, 170
    int ci1 = ((q + 1) * 256) / 3;           // 85, 170, 256
    int img = tid >> 7;              // 0..1 (wave-uniform)
    int t128 = tid & 127;
    int quad = t128 & 15;            // 4-channel group: ch = quad*4 .. quad*4+3
    int prow = t128 >> 4;            // output row 0..7 (8 px)
    int b = b2 * 2 + img;
    int hbase = img * H_STRIDE;
    int wlo = 2 * quad;              // lo-pair offset within tap record
    int whi = 32 + 2 * quad;         // hi-pair offset

    float acc[4][8];
    #pragma unroll
    for (int i = 0; i < 4; ++i)
        #pragma unroll
        for (int j = 0; j < 8; ++j) acc[i][j] = 0.f;

    #define STAGE(ci)                                                                        \
    {                                                                                        \
        const float* wsrc = wt + (size_t)(g * 256 + (ci)) * W_SLAB;                          \
        const float* h0src = h + ((size_t)(b2 * 2 + 0) * 256 + (ci)) * H_STRIDE;             \
        const float* h1src = h + ((size_t)(b2 * 2 + 1) * 256 + (ci)) * H_STRIDE;             \
        _Pragma("unroll")                                                                    \
        for (int k = 0; k < 6; ++k) {                                                        \
            int ix = k * 256 + tid;                                                          \
            if (ix < 1296)                                                                   \
                __builtin_amdgcn_global_load_lds(                                            \
                    (const unsigned int*)wsrc + ix * 4,                                      \
                    (unsigned int*)wsh + ix * 4, 16, 0, 0);                                  \
        }                                                                                    \
        if (tid < 150)                                                                       \
            __builtin_amdgcn_global_load_lds(                                                \
                (const unsigned int*)h0src + tid * 4,                                        \
                (unsigned int*)hsh + tid * 4, 16, 0, 0);                                     \
        if (tid < 150)                                                                       \
            __builtin_amdgcn_global_load_lds(                                                \
                (const unsigned int*)h1src + tid * 4,                                        \
                (unsigned int*)(hsh + H_STRIDE) + tid * 4, 16, 0, 0);                        \
    }

    STAGE(ci0);
    asm volatile("s_waitcnt vmcnt(0)" ::: "memory");
    __syncthreads();

    for (int ci = ci0; ci < ci1; ++ci) {
        #pragma unroll 3
        for (int ky = 0; ky < 9; ++ky) {
            int hr = hbase + (2 * prow + ky) * 25;
            float hv[23];
            #pragma unroll
            for (int t = 0; t < 23; ++t) hv[t] = hsh[hr + t];
            #pragma unroll
            for (int kx = 0; kx < 9; ++kx) {
                const float* wp = wsh + (ky * 9 + kx) * 64;
                float2 wa = *(const float2*)(wp + wlo);
                float2 wb = *(const float2*)(wp + whi);
                float wv[4] = {wa.x, wa.y, wb.x, wb.y};
                #pragma unroll
                for (int j = 0; j < 8; ++j) {
                    float hx = hv[2 * j + kx];
                    #pragma unroll
                    for (int i = 0; i < 4; ++i) acc[i][j] += wv[i] * hx;
                }
            }
        }
        __syncthreads();                          // all waves done reading LDS
        if (ci + 1 < ci1) STAGE(ci + 1);          // overwrite
        asm volatile("s_waitcnt vmcnt(0)" ::: "memory");
        __syncthreads();                          // staged data visible to all
    }
    #undef STAGE

    float* pp = part + ((size_t)(q * 128 + b) * 8 + g) * 4096;
    #pragma unroll
    for (int i = 0; i < 4; ++i) {
        int c64 = quad * 4 + i;
        *(float4*)(pp + c64 * 64 + prow * 8) =
            make_float4(acc[i][0], acc[i][1], acc[i][2], acc[i][3]);
        *(float4*)(pp + c64 * 64 + prow * 8 + 4) =
            make_float4(acc[i][4], acc[i][5], acc[i][6], acc[i][7]);
    }
}

// ---------------------------------------------------------------------------
// combine 3 ci-thirds + bias + squash over capsule dim -> ut[b][r][8]
// ---------------------------------------------------------------------------
__global__ void squash_u_kernel(const float* __restrict__ part,
                                const float* __restrict__ pb, float* __restrict__ ut)
{
    int b = blockIdx.x; int r = blockIdx.y * 256 + threadIdx.x;
    int c64 = r >> 6;
    const float* p0 = part + (size_t)b * 8 * 4096 + r;
    const float* p1 = p0 + 4194304;
    const float* p2 = p0 + 8388608;
    float v[8]; float sq = 0.f;
    #pragma unroll
    for (int i = 0; i < 8; ++i) {
        v[i] = p0[(size_t)i * 4096] + p1[(size_t)i * 4096] + p2[(size_t)i * 4096]
             + pb[i * 64 + c64];
        sq += v[i] * v[i];
    }
    float sc = sqrtf(sq) / (1.f + sq);
    float4 o0 = make_float4(v[0] * sc, v[1] * sc, v[2] * sc, v[3] * sc);
    float4 o1 = make_float4(v[4] * sc, v[5] * sc, v[6] * sc, v[7] * sc);
    float* o = ut + ((size_t)b * 4096 + r) * 8;
    *(float4*)o = o0; *(float4*)(o + 4) = o1;
}

// ---------------------------------------------------------------------------
// softmax stats over r (4096) per (c,b) row of logits
// ---------------------------------------------------------------------------
__global__ void softmax_stats_kernel(const float* __restrict__ logits,
                                     float* __restrict__ mbuf, float* __restrict__ sebuf)
{
    int cb = blockIdx.x; int tid = threadIdx.x;
    const float* lrow = logits + (size_t)cb * 4096;
    float mx = -1e30f;
    for (int i = tid; i < 4096; i += 256) mx = fmaxf(mx, lrow[i]);
    #pragma unroll
    for (int d = 1; d < 64; d <<= 1) mx = fmaxf(mx, __shfl_xor(mx, d));
    __shared__ float rm[4], rs[4];
    if ((tid & 63) == 0) rm[tid >> 6] = mx;
    __syncthreads();
    mx = fmaxf(fmaxf(rm[0], rm[1]), fmaxf(rm[2], rm[3]));
    float s = 0.f;
    for (int i = tid; i < 4096; i += 256) s += expf(lrow[i] - mx);
    #pragma unroll
    for (int d = 1; d < 64; d <<= 1) s += __shfl_xor(s, d);
    if ((tid & 63) == 0) rs[tid >> 6] = s;
    __syncthreads();
    if (tid == 0) {
        mbuf[cb] = mx;
        sebuf[cb] = rs[0] + rs[1] + rs[2] + rs[3];
    }
}

// ---------------------------------------------------------------------------
// routing phase A (R5-proven): per (c, 32-r chunk) partial s, deterministic
// ---------------------------------------------------------------------------
__global__ __launch_bounds__(256) void route_s_kernel(
    const float* __restrict__ logits, const float* __restrict__ ut,
    const float* __restrict__ route_w, const float* __restrict__ mbuf,
    const float* __restrict__ sebuf, float* __restrict__ spart)
{
    __shared__ __align__(16) float smem[11232];
    const int UB = 4224, PB = 8400, RB = 8928;
    int c = blockIdx.x, ch = blockIdx.y, tid = threadIdx.x;
    int r0 = ch * 32;

    {
        const float4* w4 = (const float4*)(route_w + ((size_t)c * 4096 + r0) * 128);
        #pragma unroll
        for (int k = 0; k < 4; ++k) {
            int idx = k * 256 + tid;
            float4 wv = w4[idx];
            int rl = idx >> 5, rem = (idx & 31) * 4;
            *(float4*)(smem + rl * 132 + rem) = wv;
        }
    }

    int bC = tid & 15, igC = (tid >> 4) & 7, ohC = tid >> 7;

    for (int bg = 0; bg < 8; ++bg) {
        int b0 = bg * 16;
        __syncthreads();
        {
            int bb = tid >> 4, seg = tid & 15;
            const float4* us = (const float4*)(ut + (size_t)(b0 + bb) * 32768 + (size_t)r0 * 8);
            #pragma unroll
            for (int qq = 0; qq < 4; ++qq) {
                float4 v = us[seg * 4 + qq];
                int base = UB + bb * 261 + (seg * 4 + qq) * 4;
                smem[base + 0] = v.x; smem[base + 1] = v.y;
                smem[base + 2] = v.z; smem[base + 3] = v.w;
            }
        }
        if (tid < 128) {
            int b = tid >> 3, rr = tid & 7;
            int cb = c * 128 + b0 + b;
            float m = mbuf[cb];
            float inv = 1.0f / sebuf[cb];
            float4 lv = *(const float4*)(logits + (size_t)cb * 4096 + r0 + rr * 4);
            int pbb = PB + b * 33 + rr * 4;
            smem[pbb + 0] = expf(lv.x - m) * inv;
            smem[pbb + 1] = expf(lv.y - m) * inv;
            smem[pbb + 2] = expf(lv.z - m) * inv;
            smem[pbb + 3] = expf(lv.w - m) * inv;
        }
        __syncthreads();
        float4 a0 = make_float4(0.f, 0.f, 0.f, 0.f);
        float4 a1 = make_float4(0.f, 0.f, 0.f, 0.f);
        int ub = UB + bC * 261 + igC;
        int wb = igC * 16 + ohC * 8;
        int pbb = PB + bC * 33;
        for (int rl = 0; rl < 32; ++rl) {
            float uu = smem[ub + rl * 8];
            float pr = smem[pbb + rl];
            float t1 = pr * uu;
            const float* wp = smem + rl * 132 + wb;
            float4 w0 = *(const float4*)wp;
            float4 w1 = *(const float4*)(wp + 4);
            a0.x += t1 * w0.x; a0.y += t1 * w0.y; a0.z += t1 * w0.z; a0.w += t1 * w0.w;
            a1.x += t1 * w1.x; a1.y += t1 * w1.y; a1.z += t1 * w1.z; a1.w += t1 * w1.w;
        }
        int rb = RB + tid * 9;
        smem[rb + 0] = a0.x; smem[rb + 1] = a0.y; smem[rb + 2] = a0.z; smem[rb + 3] = a0.w;
        smem[rb + 4] = a1.x; smem[rb + 5] = a1.y; smem[rb + 6] = a1.z; smem[rb + 7] = a1.w;
        __syncthreads();
        {
            int o = tid & 15, b = tid >> 4;
            int oh = o >> 3, ol = o & 7;
            float s = 0.f;
            #pragma unroll
            for (int ig = 0; ig < 8; ++ig)
                s += smem[RB + (b + 16 * ig + 128 * oh) * 9 + ol];
            spart[(size_t)ch * 20480 + (size_t)(c * 128 + b0 + b) * 16 + o] = s;
        }
    }
}

// ---------------------------------------------------------------------------
// routing phase B: s = sum_ch spart (fixed order), v = squash(s) per (c,b)
// ---------------------------------------------------------------------------
__global__ void route_v_kernel(const float* __restrict__ spart, float* __restrict__ vbuf)
{
    int cb = blockIdx.x * 64 + threadIdx.x;  // 1280
    float4 a0 = make_float4(0,0,0,0), a1 = make_float4(0,0,0,0);
    float4 a2 = make_float4(0,0,0,0), a3 = make_float4(0,0,0,0);
    for (int k = 0; k < 128; ++k) {
        const float4* p = (const float4*)(spart + (size_t)k * 20480 + (size_t)cb * 16);
        float4 b0 = p[0], b1 = p[1], b2 = p[2], b3 = p[3];
        a0.x += b0.x; a0.y += b0.y; a0.z += b0.z; a0.w += b0.w;
        a1.x += b1.x; a1.y += b1.y; a1.z += b1.z; a1.w += b1.w;
        a2.x += b2.x; a2.y += b2.y; a2.z += b2.z; a2.w += b2.w;
        a3.x += b3.x; a3.y += b3.y; a3.z += b3.z; a3.w += b3.w;
    }
    float sq = a0.x*a0.x + a0.y*a0.y + a0.z*a0.z + a0.w*a0.w
             + a1.x*a1.x + a1.y*a1.y + a1.z*a1.z + a1.w*a1.w
             + a2.x*a2.x + a2.y*a2.y + a2.z*a2.z + a2.w*a2.w
             + a3.x*a3.x + a3.y*a3.y + a3.z*a3.z + a3.w*a3.w;
    float sc = sqrtf(sq) / (1.f + sq);
    float4* vp = (float4*)(vbuf + (size_t)cb * 16);
    vp[0] = make_float4(a0.x*sc, a0.y*sc, a0.z*sc, a0.w*sc);
    vp[1] = make_float4(a1.x*sc, a1.y*sc, a1.z*sc, a1.w*sc);
    vp[2] = make_float4(a2.x*sc, a2.y*sc, a2.z*sc, a2.w*sc);
    vp[3] = make_float4(a3.x*sc, a3.y*sc, a3.z*sc, a3.w*sc);
}

// ---------------------------------------------------------------------------
// routing phase C (R5-proven): logits += prior . v
// ---------------------------------------------------------------------------
__global__ __launch_bounds__(256) void route_upd_kernel(
    float* __restrict__ logits, const float* __restrict__ ut,
    const float* __restrict__ route_w, const float* __restrict__ vbuf)
{
    __shared__ __align__(16) float smem[8400];   // wch 4224 + ubuf 4176
    const int UB = 4224;
    int c = blockIdx.x, ch = blockIdx.y, tid = threadIdx.x;
    int r0 = ch * 32;
    {
        const float4* w4 = (const float4*)(route_w + ((size_t)c * 4096 + r0) * 128);
        #pragma unroll
        for (int k = 0; k < 4; ++k) {
            int idx = k * 256 + tid;
            float4 wv = w4[idx];
            int rl = idx >> 5, rem = (idx & 31) * 4;
            *(float4*)(smem + rl * 132 + rem) = wv;
        }
    }
    int b = tid & 15, rg = tid >> 4;
    for (int bg = 0; bg < 8; ++bg) {
        int b0 = bg * 16;
        __syncthreads();
        {
            int bb = tid >> 4, seg = tid & 15;
            const float4* us = (const float4*)(ut + (size_t)(b0 + bb) * 32768 + (size_t)r0 * 8);
            #pragma unroll
            for (int qq = 0; qq < 4; ++qq) {
                float4 v = us[seg * 4 + qq];
                int base = UB + bb * 261 + (seg * 4 + qq) * 4;
                smem[base + 0] = v.x; smem[base + 1] = v.y;
                smem[base + 2] = v.z; smem[base + 3] = v.w;
            }
        }
        __syncthreads();
        int cb = c * 128 + b0 + b;
        const float4* vp = (const float4*)(vbuf + (size_t)cb * 16);
        float4 v0 = vp[0], v1 = vp[1], v2 = vp[2], v3 = vp[3];
        #pragma unroll
        for (int jj = 0; jj < 2; ++jj) {
            int rl = rg * 2 + jj;
            float4 p0 = make_float4(0,0,0,0), p1 = make_float4(0,0,0,0);
            float4 p2 = make_float4(0,0,0,0), p3 = make_float4(0,0,0,0);
            int ub = UB + b * 261 + rl * 8;
            #pragma unroll
            for (int i = 0; i < 8; ++i) {
                float uu = smem[ub + i];
                const float* wp = smem + rl * 132 + i * 16;
                float4 w0 = *(const float4*)wp;
                float4 w1 = *(const float4*)(wp + 4);
                float4 w2 = *(const float4*)(wp + 8);
                float4 w3 = *(const float4*)(wp + 12);
                p0.x += uu*w0.x; p0.y += uu*w0.y; p0.z += uu*w0.z; p0.w += uu*w0.w;
                p1.x += uu*w1.x; p1.y += uu*w1.y; p1.z += uu*w1.z; p1.w += uu*w1.w;
                p2.x += uu*w2.x; p2.y += uu*w2.y; p2.z += uu*w2.z; p2.w += uu*w2.w;
                p3.x += uu*w3.x; p3.y += uu*w3.y; p3.z += uu*w3.z; p3.w += uu*w3.w;
            }
            float delta = p0.x*v0.x + p0.y*v0.y + p0.z*v0.z + p0.w*v0.w
                        + p1.x*v1.x + p1.y*v1.y + p1.z*v1.z + p1.w*v1.w
                        + p2.x*v2.x + p2.y*v2.y + p2.z*v2.z + p2.w*v2.w
                        + p3.x*v3.x + p3.y*v3.y + p3.z*v3.z + p3.w*v3.w;
            logits[(size_t)cb * 4096 + r0 + rl] += delta;
        }
    }
}

// ---------------------------------------------------------------------------
// classes softmax + argmax one-hot mask -> z
// ---------------------------------------------------------------------------
__global__ void caps_out_kernel(const float* __restrict__ vbuf,
                                float* __restrict__ out_classes, float* __restrict__ zbuf)
{
    int b = threadIdx.x;  // 128
    float norms[10];
    #pragma unroll
    for (int c = 0; c < 10; ++c) {
        const float* vp = vbuf + (size_t)(c * 128 + b) * 16;
        float sq = 0.f;
        #pragma unroll
        for (int o = 0; o < 16; ++o) sq += vp[o] * vp[o];
        norms[c] = sqrtf(sq);
    }
    float mx = norms[0]; int am = 0;
    #pragma unroll
    for (int c = 1; c < 10; ++c) if (norms[c] > mx) { mx = norms[c]; am = c; }
    float se = 0.f; float e[10];
    #pragma unroll
    for (int c = 0; c < 10; ++c) { e[c] = expf(norms[c] - mx); se += e[c]; }
    float isd = 1.f / se;
    #pragma unroll
    for (int c = 0; c < 10; ++c) out_classes[b * 10 + c] = e[c] * isd;
    #pragma unroll
    for (int c = 0; c < 10; ++c) {
        const float* vp = vbuf + (size_t)(c * 128 + b) * 16;
        #pragma unroll
        for (int o = 0; o < 16; ++o)
            zbuf[b * 160 + c * 16 + o] = (c == am) ? vp[o] : 0.f;
    }
}

// ---------------------------------------------------------------------------
// generator stage 1: z[128,160] x g1_w[160,256*16] -> t1[128,4096] (raw)
// ---------------------------------------------------------------------------
__global__ void gen1_kernel(const float* __restrict__ z, const float* __restrict__ w,
                            float* __restrict__ out)
{
    int idx = blockIdx.x * 256 + threadIdx.x;  // 524288
    int j = idx & 4095; int b = idx >> 12;
    const float* zp = z + b * 160;
    float a = 0.f;
    #pragma unroll 4
    for (int ci = 0; ci < 160; ++ci) a += zp[ci] * w[(size_t)ci * 4096 + j];
    out[idx] = a;
}

// ---------------------------------------------------------------------------
// batchnorm stats (training-mode) per channel over (N,H,W) of RAW tensor
// ---------------------------------------------------------------------------
template <int C, int HW>
__global__ void bn_stats_kernel(const float* __restrict__ t, const float* __restrict__ g,
                                const float* __restrict__ beta,
                                float* __restrict__ scale, float* __restrict__ shift)
{
    int co = blockIdx.x; int tid = threadIdx.x;
    float s = 0.f, s2 = 0.f;
    for (int i = tid; i < NB * HW; i += 256) {
        int b = i / HW, hw = i - b * HW;
        float v = t[((size_t)b * C + co) * HW + hw];
        s += v; s2 += v * v;
    }
    #pragma unroll
    for (int d = 1; d < 64; d <<= 1) { s += __shfl_xor(s, d); s2 += __shfl_xor(s2, d); }
    __shared__ float rs[4], rs2[4];
    if ((tid & 63) == 0) { rs[tid >> 6] = s; rs2[tid >> 6] = s2; }
    __syncthreads();
    if (tid == 0) {
        float S = rs[0] + rs[1] + rs[2] + rs[3];
        float S2 = rs2[0] + rs2[1] + rs2[2] + rs2[3];
        const float n = (float)(NB * HW);
        float mean = S / n;
        float var = S2 / n - mean * mean;
        float r = 1.f / sqrtf(var + 1e-5f);
        scale[co] = g[co] * r;
        shift[co] = beta[co] - mean * g[co] * r;
    }
}

// ---------------------------------------------------------------------------
// LDS-staged transposed conv (k=4,s=2,p=1): thread owns one (co,oy) row.
// BN: apply relu(in*scale+shift) while staging input (fused bn_apply).
// TANH: apply tanh to outputs (final stage).
// ---------------------------------------------------------------------------
template <int Ci, int Co, int S, int SPLIT, bool BN, bool TANH>
__global__ __launch_bounds__(256) void deconv_row_kernel(
    const float* __restrict__ in, const float* __restrict__ w,
    const float* __restrict__ scale, const float* __restrict__ shift,
    float* __restrict__ out)
{
    constexpr int OS = 2 * S;
    constexpr int ROWS = Co * OS;
    constexpr int RPB = ROWS / SPLIT;
    __shared__ __align__(16) float ish[Ci * S * S];
    int b = blockIdx.x, rb = blockIdx.y, tid = threadIdx.x;
    const float4* src = (const float4*)(in + (size_t)b * Ci * S * S);
    for (int i = tid; i < Ci * S * S / 4; i += 256) {
        float4 v = src[i];
        if (BN) {
            int cin = (i * 4) / (S * S);
            float sc = scale[cin], sh = shift[cin];
            v.x = fmaxf(v.x * sc + sh, 0.f);
            v.y = fmaxf(v.y * sc + sh, 0.f);
            v.z = fmaxf(v.z * sc + sh, 0.f);
            v.w = fmaxf(v.w * sc + sh, 0.f);
        }
        ((float4*)ish)[i] = v;
    }
    __syncthreads();

    for (int r = rb * RPB + tid; r < (rb + 1) * RPB; r += 256) {
        int co = r / OS, oy = r % OS;
        float acc[OS];
        #pragma unroll
        for (int j = 0; j < OS; ++j) acc[j] = 0.f;
        int p = (oy + 1) & 1;                      // ky parity
        for (int ci = 0; ci < Ci; ++ci) {
            const float* wci = w + ((size_t)ci * Co + co) * 16;
            #pragma unroll
            for (int t = 0; t < 2; ++t) {
                int ky = p + 2 * t;
                int iy = (oy + 1 - ky) >> 1;       // exact (even numerator)
                if (iy < 0 || iy >= S) continue;
                float4 wv = *(const float4*)(wci + ky * 4);
                const float* irow = ish + (ci * S + iy) * S;
                #pragma unroll
                for (int ox = 0; ox < OS; ++ox) {
                    int q = (ox + 1) & 1;
                    int ix0 = (ox + 1 - q) >> 1;   // kx = q
                    int ix1 = ix0 - 1;             // kx = q+2
                    float wk0 = q ? wv.y : wv.x;
                    float wk2 = q ? wv.w : wv.z;
                    if (ix0 < S)  acc[ox] += wk0 * irow[ix0];
                    if (ix1 >= 0) acc[ox] += wk2 * irow[ix1];
                }
            }
        }
        if (TANH) {
            #pragma unroll
            for (int j = 0; j < OS; ++j) acc[j] = tanhf(acc[j]);
        }
        float* orow = out + ((size_t)(b * Co + co) * OS + oy) * OS;
        #pragma unroll
        for (int j = 0; j < OS; j += 4)
            *(float4*)(orow + j) = make_float4(acc[j], acc[j+1], acc[j+2], acc[j+3]);
    }
}

// ---------------------------------------------------------------------------
extern "C" void kernel_launch(void* const* d_in, const int* in_sizes, int n_in,
                              void* d_out, int out_size, void* d_ws, size_t ws_size,
                              hipStream_t stream)
{
    const float* x       = (const float*)d_in[0];
    const float* conv1_w = (const float*)d_in[1];
    const float* conv1_b = (const float*)d_in[2];
    const float* prim_w  = (const float*)d_in[3];
    const float* prim_b  = (const float*)d_in[4];
    const float* route_w = (const float*)d_in[5];
    const float* g1_w    = (const float*)d_in[6];
    const float* g2_w    = (const float*)d_in[7];
    const float* g3_w    = (const float*)d_in[8];
    const float* g4_w    = (const float*)d_in[9];
    const float* bn1_g   = (const float*)d_in[10];
    const float* bn1_b   = (const float*)d_in[11];
    const float* bn2_g   = (const float*)d_in[12];
    const float* bn2_b   = (const float*)d_in[13];
    const float* bn3_g   = (const float*)d_in[14];
    const float* bn3_b   = (const float*)d_in[15];
    float* outf = (float*)d_out;

    // ws layout (floats), lifetime-aliased. Total 42.86M floats = 171 MB
    // (under the 176 MB proven in R2-R12):
    //   h    [0, 19660800)            conv1 -> prim
    //   wt   [+19660800, 10616832)    transpose -> prim; then logits(5242880)+ut(4194304)
    //   part [+30277632, 12582912)    prim(3 thirds) -> squash; then smalls+t-bufs+spart
    float* ws = (float*)d_ws;
    float* h      = ws;
    float* wt     = h + 19660800;
    float* part   = wt + 10616832;
    float* logits = wt;
    float* ut     = wt + 5242880;
    float* mbuf   = part;               // 1280
    float* sebuf  = part + 1280;        // 1280
    float* vbuf   = part + 2560;        // 20480
    float* zbuf   = part + 23040;       // 20480
    float* bnsc   = part + 64000;       // 896
    float* t1b    = part + 64896;       // 524288
    float* t2b    = part + 589184;      // 1048576
    float* t3b    = part + 1637760;     // 2097152  -> ends 3734912
    float* spart  = part + 4194304;     // 2621440  -> ends 6815744 (< 12582912)

    // stem + primary capsules
    primw_transpose_kernel<<<dim3(2048), 128, 0, stream>>>(prim_w, wt);
    conv1_kernel<<<dim3(128, 32), 192, 0, stream>>>(x, conv1_w, conv1_b, h);
    prim_conv_kernel<<<dim3(64, 8, 3), 256, 0, stream>>>(h, wt, part);
    squash_u_kernel<<<dim3(128, 16), 256, 0, stream>>>(part, prim_b, ut);

    // dynamic routing (3 iterations), deterministic two-stage reduction
    hipMemsetAsync(logits, 0, (size_t)5242880 * sizeof(float), stream);
    for (int it = 0; it < 3; ++it) {
        softmax_stats_kernel<<<dim3(1280), 256, 0, stream>>>(logits, mbuf, sebuf);
        route_s_kernel<<<dim3(10, 128), 256, 0, stream>>>(logits, ut, route_w, mbuf, sebuf, spart);
        route_v_kernel<<<dim3(20), 64, 0, stream>>>(spart, vbuf);
        if (it < 2)
            route_upd_kernel<<<dim3(10, 128), 256, 0, stream>>>(logits, ut, route_w, vbuf);
    }
    caps_out_kernel<<<dim3(1), 128, 0, stream>>>(vbuf, outf, zbuf);

    // generator: raw deconv outputs in t-buffers; BN+ReLU fused into next stage
    gen1_kernel<<<dim3(2048), 256, 0, stream>>>(zbuf, g1_w, t1b);
    bn_stats_kernel<256, 16><<<dim3(256), 256, 0, stream>>>(t1b, bn1_g, bn1_b, bnsc, bnsc + 256);

    deconv_row_kernel<256, 128, 4, 4, true, false>
        <<<dim3(128, 4), 256, 0, stream>>>(t1b, g2_w, bnsc, bnsc + 256, t2b);
    bn_stats_kernel<128, 64><<<dim3(128), 256, 0, stream>>>(t2b, bn2_g, bn2_b, bnsc + 512, bnsc + 640);

    deconv_row_kernel<128, 64, 8, 4, true, false>
        <<<dim3(128, 4), 256, 0, stream>>>(t2b, g3_w, bnsc + 512, bnsc + 640, t3b);
    bn_stats_kernel<64, 256><<<dim3(64), 256, 0, stream>>>(t3b, bn3_g, bn3_b, bnsc + 768, bnsc + 832);

    deconv_row_kernel<64, 3, 16, 1, true, true>
        <<<dim3(128, 1), 256, 0, stream>>>(t3b, g4_w, bnsc + 768, bnsc + 832, outf + 1280);
}